// Round 3
// baseline (230.392 us; speedup 1.0000x reference)
//
#include <hip/hip_runtime.h>
#include <stdint.h>

#define N_  32
#define C_  128
#define H_  56
#define W_  56
#define HW_ 3136
#define P_  128
#define PB  16
#define PSPLIT 8
#define NPIX (N_*HW_)           // 100352
#define NGRP (NPIX/4)           // 25088 4-pixel groups

// Workspace layout (bytes):
//   abits : NPIX*16      = 1,605,632   (uint4 per pixel: 128 sign bits)
//   wbits : P*9*16       = 18,432
//   negA  : P*4
//   K     : 9*P*4
#define ABITS_BYTES (NPIX*16)
#define WBITS_BYTES (P_*9*16)

// ------- pack x sign bits: one thread per (pixel, 32-ch word) ----------------
__global__ __launch_bounds__(256) void pack_x_kernel(const float* __restrict__ x,
                                                     uint32_t* __restrict__ abits_w) {
    int t = blockIdx.x * 256 + threadIdx.x;   // 0 .. NPIX*4, grid exact (1568 blocks)
    int i = t >> 2, j = t & 3;                // pixel, word
    int n = i / HW_, r = i % HW_;
    const float* px = x + (size_t)n * C_ * HW_ + (size_t)(j * 32) * HW_ + r;
    uint32_t wbit = 0;
    #pragma unroll
    for (int c = 0; c < 32; ++c)
        if (px[(size_t)c * HW_] >= 0.f) wbit |= 1u << c;
    abits_w[t] = wbit;
}

// ------- fused: pack weights + BN fold + border-class K table ----------------
__global__ __launch_bounds__(1024) void prep_kernel(const float* __restrict__ weight,
        const float* __restrict__ bias, const float* __restrict__ gamma,
        const float* __restrict__ beta, const float* __restrict__ mean,
        const float* __restrict__ var,
        uint32_t* __restrict__ wbits, float* __restrict__ K, float* __restrict__ negA) {
    __shared__ uint32_t sw[P_ * 36];     // 4608 B
    __shared__ float sA[P_], sB0[P_];
    int tid = threadIdx.x;

    for (int gid = tid; gid < P_ * 9; gid += 1024) {
        int p = gid / 9, t = gid % 9;        // t = kh*3+kw
        const float* pw = weight + (size_t)p * C_ * 9 + t;
        uint32_t w[4] = {0, 0, 0, 0};
        #pragma unroll 16
        for (int c = 0; c < C_; ++c)
            if (pw[(size_t)c * 9] >= 0.f) w[c >> 5] |= 1u << (c & 31);
        #pragma unroll
        for (int q = 0; q < 4; ++q) { sw[gid*4+q] = w[q]; wbits[gid*4+q] = w[q]; }
    }
    if (tid < P_) {
        float inv = gamma[tid] * rsqrtf(var[tid] + 1e-5f);
        sA[tid]  = inv;
        sB0[tid] = bias[tid] * inv + beta[tid] - mean[tid] * inv;
        negA[tid] = -2.f * inv;
    }
    __syncthreads();

    for (int gid = tid; gid < 9 * P_; gid += 1024) {
        int cls = gid / P_, p = gid % P_;
        int chc = cls / 3, cwc = cls % 3;
        int corr = 0;
        #pragma unroll
        for (int t = 0; t < 9; ++t) {
            int kh = t / 3, kw = t % 3;
            bool inval = (chc == 0 && kh == 0) || (chc == 2 && kh == 2) ||
                         (cwc == 0 && kw == 0) || (cwc == 2 && kw == 2);
            if (inval)
                corr += __popc(sw[p*36+t*4+0]) + __popc(sw[p*36+t*4+1])
                      + __popc(sw[p*36+t*4+2]) + __popc(sw[p*36+t*4+3]);
        }
        int V = ((chc == 1) ? 3 : 2) * ((cwc == 1) ? 3 : 2);
        K[gid] = (128.f * (float)V + 2.f * (float)corr) * sA[p] + sB0[p];
    }
}

// ------- binary conv + BN + residual: 4-pixel strip x 16 channels/thread -----
__global__ __launch_bounds__(256) void bconv_kernel(
        const uint4* __restrict__ abits, const uint4* __restrict__ wbits4,
        const float* __restrict__ Kg, const float* __restrict__ negAg,
        const float* __restrict__ x, float* __restrict__ out) {
    __shared__ uint4  sw4[PB * 9];       // 2304 B
    __shared__ float  sK[9 * PB];        // 576 B
    __shared__ float  sNegA[PB];

    int tid   = threadIdx.x;
    int pbase = (blockIdx.x & (PSPLIT - 1)) * PB;
    int g     = (blockIdx.x >> 3) * 256 + tid;   // 4-pixel group id, grid exact

    if (tid < PB * 9) sw4[tid] = wbits4[pbase * 9 + tid];
    if (tid < 9 * PB) sK[tid] = Kg[(tid / PB) * P_ + pbase + (tid % PB)];
    if (tid < PB)     sNegA[tid] = negAg[pbase + tid];
    __syncthreads();

    int n  = g / (HW_ / 4);
    int rr = g % (HW_ / 4);
    int r  = rr * 4;
    int h  = r / W_;
    int w  = r % W_;                     // w in {0,4,...,52}

    // activation window: rows h-1..h+1, cols w-1..w+4
    uint4 a[3][6];
    const uint4* ab = abits + (size_t)n * HW_;
    #pragma unroll
    for (int dr = 0; dr < 3; ++dr) {
        int hh = h + dr - 1;
        bool vr = (unsigned)hh < H_;
        #pragma unroll
        for (int dc = 0; dc < 6; ++dc) {
            int cc = w + dc - 1;
            a[dr][dc] = (vr && ((unsigned)cc < W_)) ? ab[hh * W_ + cc]
                                                    : make_uint4(0u, 0u, 0u, 0u);
        }
    }
    int chc  = (h == 0) ? 0 : ((h == H_ - 1) ? 2 : 1);
    int cls0 = chc * 3 + ((w == 0) ? 0 : 1);
    int cls1 = chc * 3 + 1;                          // pixels 1,2 never at w-border
    int cls3 = chc * 3 + ((w + 3 == W_ - 1) ? 2 : 1);

    const float* xr = x   + ((size_t)n * P_ + pbase) * HW_ + r;
    float*       po = out + ((size_t)n * P_ + pbase) * HW_ + r;

    #pragma unroll 2
    for (int p = 0; p < PB; ++p) {
        float4 xv = *(const float4*)(xr + (size_t)p * HW_);
        int c0 = 0, c1 = 0, c2 = 0, c3 = 0;
        #pragma unroll
        for (int t = 0; t < 9; ++t) {
            uint4 wv = sw4[p * 9 + t];
            int tr = t / 3, tc = t % 3;
            c0 += __popc(a[tr][tc+0].x ^ wv.x) + __popc(a[tr][tc+0].y ^ wv.y)
                + __popc(a[tr][tc+0].z ^ wv.z) + __popc(a[tr][tc+0].w ^ wv.w);
            c1 += __popc(a[tr][tc+1].x ^ wv.x) + __popc(a[tr][tc+1].y ^ wv.y)
                + __popc(a[tr][tc+1].z ^ wv.z) + __popc(a[tr][tc+1].w ^ wv.w);
            c2 += __popc(a[tr][tc+2].x ^ wv.x) + __popc(a[tr][tc+2].y ^ wv.y)
                + __popc(a[tr][tc+2].z ^ wv.z) + __popc(a[tr][tc+2].w ^ wv.w);
            c3 += __popc(a[tr][tc+3].x ^ wv.x) + __popc(a[tr][tc+3].y ^ wv.y)
                + __popc(a[tr][tc+3].z ^ wv.z) + __popc(a[tr][tc+3].w ^ wv.w);
        }
        float na = sNegA[p];
        float4 ov;
        ov.x = fmaf((float)c0, na, sK[cls0 * PB + p]) + xv.x;
        ov.y = fmaf((float)c1, na, sK[cls1 * PB + p]) + xv.y;
        ov.z = fmaf((float)c2, na, sK[cls1 * PB + p]) + xv.z;
        ov.w = fmaf((float)c3, na, sK[cls3 * PB + p]) + xv.w;
        *(float4*)(po + (size_t)p * HW_) = ov;
    }
}

extern "C" void kernel_launch(void* const* d_in, const int* in_sizes, int n_in,
                              void* d_out, int out_size, void* d_ws, size_t ws_size,
                              hipStream_t stream) {
    const float* x      = (const float*)d_in[0];
    const float* weight = (const float*)d_in[1];
    const float* bias   = (const float*)d_in[2];
    const float* gamma  = (const float*)d_in[3];
    const float* beta   = (const float*)d_in[4];
    const float* mean   = (const float*)d_in[5];
    const float* var    = (const float*)d_in[6];
    float* out = (float*)d_out;

    uint8_t*  ws    = (uint8_t*)d_ws;
    uint4*    abits = (uint4*)ws;
    uint32_t* wbits = (uint32_t*)(ws + ABITS_BYTES);
    float*    negA  = (float*)(ws + ABITS_BYTES + WBITS_BYTES);
    float*    K     = negA + P_;

    pack_x_kernel<<<(NPIX * 4) / 256, 256, 0, stream>>>(x, (uint32_t*)abits);
    prep_kernel<<<1, 1024, 0, stream>>>(weight, bias, gamma, beta, mean, var, wbits, K, negA);
    bconv_kernel<<<(NGRP / 256) * PSPLIT, 256, 0, stream>>>(abits, (const uint4*)wbits, K, negA, x, out);
}

// Round 4
// 169.387 us; speedup vs baseline: 1.3602x; 1.3602x over previous
//
#include <hip/hip_runtime.h>
#include <stdint.h>

#define N_  32
#define C_  128
#define H_  56
#define W_  56
#define HW_ 3136
#define P_  128
#define PB  16
#define PSPLIT 8
#define NPIX (N_*HW_)           // 100352
#define NGRP (NPIX/4)           // 25088 4-pixel strips

// Workspace layout (bytes):
//   abits : NPIX*16      = 1,605,632   (uint4 per pixel: 128 sign bits)
//   wbits : P*9*16       = 18,432
//   negA  : P*4
//   K     : 9*P*4
#define ABITS_BYTES (NPIX*16)
#define WBITS_BYTES (P_*9*16)

// ------- pack x sign bits: one thread per (pixel, 32-ch word) ----------------
__global__ __launch_bounds__(256) void pack_x_kernel(const float* __restrict__ x,
                                                     uint32_t* __restrict__ abits_w) {
    int t = blockIdx.x * 256 + threadIdx.x;   // 0 .. NPIX*4, grid exact (1568 blocks)
    int i = t >> 2, j = t & 3;                // pixel, word
    int n = i / HW_, r = i % HW_;
    const float* px = x + (size_t)n * C_ * HW_ + (size_t)(j * 32) * HW_ + r;
    uint32_t wbit = 0;
    #pragma unroll
    for (int c = 0; c < 32; ++c)
        if (px[(size_t)c * HW_] >= 0.f) wbit |= 1u << c;
    abits_w[t] = wbit;
}

// ------- pack weights: one WAVE per (p, tap, 64-ch half) via ballot ----------
__global__ __launch_bounds__(256) void pack_w_kernel(const float* __restrict__ weight,
                                                     uint32_t* __restrict__ wbits) {
    int gt   = blockIdx.x * 256 + threadIdx.x;   // 576 blocks -> 2304 waves
    int wid  = gt >> 6;
    int lane = gt & 63;
    int p    = wid / 18;
    int rem  = wid % 18;
    int t    = rem >> 1;          // tap
    int half = rem & 1;           // channel half
    int c    = half * 64 + lane;
    float v  = weight[((size_t)p * C_ + c) * 9 + t];
    unsigned long long m = __ballot(v >= 0.f);
    if (lane == 0) {
        wbits[(p * 9 + t) * 4 + half * 2 + 0] = (uint32_t)m;
        wbits[(p * 9 + t) * 4 + half * 2 + 1] = (uint32_t)(m >> 32);
    }
}

// ------- BN fold + border-class K table --------------------------------------
__global__ __launch_bounds__(256) void ktab_kernel(const uint32_t* __restrict__ wbits,
        const float* __restrict__ bias, const float* __restrict__ gamma,
        const float* __restrict__ beta, const float* __restrict__ mean,
        const float* __restrict__ var,
        float* __restrict__ K, float* __restrict__ negA) {
    int gid = blockIdx.x * 256 + threadIdx.x;
    if (gid < 9 * P_) {
        int cls = gid / P_, p = gid % P_;
        int chc = cls / 3, cwc = cls % 3;
        int corr = 0;
        #pragma unroll
        for (int t = 0; t < 9; ++t) {
            int kh = t / 3, kw = t % 3;
            bool inval = (chc == 0 && kh == 0) || (chc == 2 && kh == 2) ||
                         (cwc == 0 && kw == 0) || (cwc == 2 && kw == 2);
            if (inval)
                corr += __popc(wbits[p*36+t*4+0]) + __popc(wbits[p*36+t*4+1])
                      + __popc(wbits[p*36+t*4+2]) + __popc(wbits[p*36+t*4+3]);
        }
        int V = ((chc == 1) ? 3 : 2) * ((cwc == 1) ? 3 : 2);
        float inv = gamma[p] * rsqrtf(var[p] + 1e-5f);
        float b0  = bias[p] * inv + beta[p] - mean[p] * inv;
        K[gid] = (128.f * (float)V + 2.f * (float)corr) * inv + b0;
    }
    if (gid < P_) {
        float inv = gamma[gid] * rsqrtf(var[gid] + 1e-5f);
        negA[gid] = -2.f * inv;
    }
}

// ------- binary conv + BN + residual: 4-pixel strip x 16 channels/thread -----
// Weights are read straight from global with wave-uniform indices -> the
// compiler scalarizes them (s_load_dwordx4), freeing the LDS pipe and VGPRs.
__global__ __launch_bounds__(256) void bconv_kernel(
        const uint4* __restrict__ abits, const uint4* __restrict__ wbits4,
        const float* __restrict__ Kg, const float* __restrict__ negAg,
        const float* __restrict__ x, float* __restrict__ out) {
    __shared__ float sK[9 * PB];         // 576 B
    __shared__ float sNegA[PB];

    int tid   = threadIdx.x;
    int pbase = (blockIdx.x & (PSPLIT - 1)) * PB;
    int g     = (blockIdx.x >> 3) * 256 + tid;   // strip id, grid exact

    if (tid < 9 * PB) sK[tid] = Kg[(tid / PB) * P_ + pbase + (tid % PB)];
    if (tid < PB)     sNegA[tid] = negAg[pbase + tid];
    __syncthreads();

    int n  = g / (HW_ / 4);
    int rr = g % (HW_ / 4);
    int r  = rr * 4;
    int h  = r / W_;
    int w  = r % W_;                     // w in {0,4,...,52}

    // activation window: rows h-1..h+1, cols w-1..w+4
    uint4 a[3][6];
    const uint4* ab = abits + (size_t)n * HW_;
    #pragma unroll
    for (int dr = 0; dr < 3; ++dr) {
        int hh = h + dr - 1;
        bool vr = (unsigned)hh < H_;
        #pragma unroll
        for (int dc = 0; dc < 6; ++dc) {
            int cc = w + dc - 1;
            a[dr][dc] = (vr && ((unsigned)cc < W_)) ? ab[hh * W_ + cc]
                                                    : make_uint4(0u, 0u, 0u, 0u);
        }
    }
    int chc  = (h == 0) ? 0 : ((h == H_ - 1) ? 2 : 1);
    int cls0 = chc * 3 + ((w == 0) ? 0 : 1);
    int cls1 = chc * 3 + 1;                          // middle pixels never at w-border
    int cls3 = chc * 3 + ((w + 3 == W_ - 1) ? 2 : 1);

    const float* xr = x   + ((size_t)n * P_ + pbase) * HW_ + r;
    float*       po = out + ((size_t)n * P_ + pbase) * HW_ + r;
    const uint4* wb = wbits4 + (size_t)pbase * 9;    // wave-uniform base

    for (int p = 0; p < PB; ++p) {
        float4 xv = *(const float4*)(xr + (size_t)p * HW_);
        int c0 = 0, c1 = 0, c2 = 0, c3 = 0;
        #pragma unroll
        for (int t = 0; t < 9; ++t) {
            uint4 wv = wb[p * 9 + t];                // uniform -> SGPRs
            int tr = t / 3, tc = t % 3;
            c0 += __popc(a[tr][tc+0].x ^ wv.x) + __popc(a[tr][tc+0].y ^ wv.y)
                + __popc(a[tr][tc+0].z ^ wv.z) + __popc(a[tr][tc+0].w ^ wv.w);
            c1 += __popc(a[tr][tc+1].x ^ wv.x) + __popc(a[tr][tc+1].y ^ wv.y)
                + __popc(a[tr][tc+1].z ^ wv.z) + __popc(a[tr][tc+1].w ^ wv.w);
            c2 += __popc(a[tr][tc+2].x ^ wv.x) + __popc(a[tr][tc+2].y ^ wv.y)
                + __popc(a[tr][tc+2].z ^ wv.z) + __popc(a[tr][tc+2].w ^ wv.w);
            c3 += __popc(a[tr][tc+3].x ^ wv.x) + __popc(a[tr][tc+3].y ^ wv.y)
                + __popc(a[tr][tc+3].z ^ wv.z) + __popc(a[tr][tc+3].w ^ wv.w);
        }
        float na = sNegA[p];
        float4 ov;
        ov.x = fmaf((float)c0, na, sK[cls0 * PB + p]) + xv.x;
        ov.y = fmaf((float)c1, na, sK[cls1 * PB + p]) + xv.y;
        ov.z = fmaf((float)c2, na, sK[cls1 * PB + p]) + xv.z;
        ov.w = fmaf((float)c3, na, sK[cls3 * PB + p]) + xv.w;
        *(float4*)(po + (size_t)p * HW_) = ov;
    }
}

extern "C" void kernel_launch(void* const* d_in, const int* in_sizes, int n_in,
                              void* d_out, int out_size, void* d_ws, size_t ws_size,
                              hipStream_t stream) {
    const float* x      = (const float*)d_in[0];
    const float* weight = (const float*)d_in[1];
    const float* bias   = (const float*)d_in[2];
    const float* gamma  = (const float*)d_in[3];
    const float* beta   = (const float*)d_in[4];
    const float* mean   = (const float*)d_in[5];
    const float* var    = (const float*)d_in[6];
    float* out = (float*)d_out;

    uint8_t*  ws    = (uint8_t*)d_ws;
    uint4*    abits = (uint4*)ws;
    uint32_t* wbits = (uint32_t*)(ws + ABITS_BYTES);
    float*    negA  = (float*)(ws + ABITS_BYTES + WBITS_BYTES);
    float*    K     = negA + P_;

    pack_x_kernel<<<(NPIX * 4) / 256, 256, 0, stream>>>(x, (uint32_t*)abits);
    pack_w_kernel<<<(P_ * 9 * 2 * 64) / 256, 256, 0, stream>>>(weight, wbits);
    ktab_kernel<<<5, 256, 0, stream>>>(wbits, bias, gamma, beta, mean, var, K, negA);
    bconv_kernel<<<(NGRP / 256) * PSPLIT, 256, 0, stream>>>(abits, (const uint4*)wbits, K, negA, x, out);
}

// Round 5
// 164.346 us; speedup vs baseline: 1.4019x; 1.0307x over previous
//
#include <hip/hip_runtime.h>
#include <stdint.h>

#define N_  32
#define C_  128
#define H_  56
#define W_  56
#define HW_ 3136
#define P_  128
#define PB  8
#define PSPLIT 16
#define NPIX (N_*HW_)           // 100352
#define NGRP (NPIX/4)           // 25088 4-pixel strips

// Workspace layout (bytes):
//   abits : NPIX*16      = 1,605,632   (uint4 per pixel: 128 sign bits)
//   wbits : P*9*16       = 18,432
//   negA  : P*4
//   K     : 9*P*4
#define ABITS_BYTES (NPIX*16)
#define WBITS_BYTES (P_*9*16)

// ------- pack x sign bits: word-plane-major so lanes = consecutive pixels ----
// block b: word j = b&3, pixels (b>>2)*256 + tid. Every load is a fully
// coalesced 256B wave-load; one strided dword store per thread.
__global__ __launch_bounds__(256) void pack_x_kernel(const float* __restrict__ x,
                                                     uint32_t* __restrict__ abits_w) {
    int b   = blockIdx.x;
    int j   = b & 3;                          // 32-channel word
    int i   = (b >> 2) * 256 + threadIdx.x;   // pixel id, grid exact
    int n   = i / HW_, r = i % HW_;
    const float* px = x + ((size_t)n * C_ + j * 32) * HW_ + r;
    uint32_t wbit = 0;
    #pragma unroll
    for (int c = 0; c < 32; ++c)
        if (px[(size_t)c * HW_] >= 0.f) wbit |= 1u << c;
    abits_w[(size_t)i * 4 + j] = wbit;
}

// ------- pack weights: one WAVE per (p, tap, 64-ch half) via ballot ----------
__global__ __launch_bounds__(256) void pack_w_kernel(const float* __restrict__ weight,
                                                     uint32_t* __restrict__ wbits) {
    int gt   = blockIdx.x * 256 + threadIdx.x;   // 576 blocks -> 2304 waves
    int wid  = gt >> 6;
    int lane = gt & 63;
    int p    = wid / 18;
    int rem  = wid % 18;
    int t    = rem >> 1;          // tap
    int half = rem & 1;           // channel half
    int c    = half * 64 + lane;
    float v  = weight[((size_t)p * C_ + c) * 9 + t];
    unsigned long long m = __ballot(v >= 0.f);
    if (lane == 0) {
        wbits[(p * 9 + t) * 4 + half * 2 + 0] = (uint32_t)m;
        wbits[(p * 9 + t) * 4 + half * 2 + 1] = (uint32_t)(m >> 32);
    }
}

// ------- BN fold + border-class K table --------------------------------------
__global__ __launch_bounds__(256) void ktab_kernel(const uint32_t* __restrict__ wbits,
        const float* __restrict__ bias, const float* __restrict__ gamma,
        const float* __restrict__ beta, const float* __restrict__ mean,
        const float* __restrict__ var,
        float* __restrict__ K, float* __restrict__ negA) {
    int gid = blockIdx.x * 256 + threadIdx.x;
    if (gid < 9 * P_) {
        int cls = gid / P_, p = gid % P_;
        int chc = cls / 3, cwc = cls % 3;
        int corr = 0;
        #pragma unroll
        for (int t = 0; t < 9; ++t) {
            int kh = t / 3, kw = t % 3;
            bool inval = (chc == 0 && kh == 0) || (chc == 2 && kh == 2) ||
                         (cwc == 0 && kw == 0) || (cwc == 2 && kw == 2);
            if (inval)
                corr += __popc(wbits[p*36+t*4+0]) + __popc(wbits[p*36+t*4+1])
                      + __popc(wbits[p*36+t*4+2]) + __popc(wbits[p*36+t*4+3]);
        }
        int V = ((chc == 1) ? 3 : 2) * ((cwc == 1) ? 3 : 2);
        float inv = gamma[p] * rsqrtf(var[p] + 1e-5f);
        float b0  = bias[p] * inv + beta[p] - mean[p] * inv;
        K[gid] = (128.f * (float)V + 2.f * (float)corr) * inv + b0;
    }
    if (gid < P_) {
        float inv = gamma[gid] * rsqrtf(var[gid] + 1e-5f);
        negA[gid] = -2.f * inv;
    }
}

// ------- binary conv + BN + residual: 4-pixel strip x 8 channels/thread ------
// PSPLIT=16 -> 1568 blocks (6.1/CU) for latency hiding; weights stay in
// SGPRs via wave-uniform global loads.
__global__ __launch_bounds__(256) void bconv_kernel(
        const uint4* __restrict__ abits, const uint4* __restrict__ wbits4,
        const float* __restrict__ Kg, const float* __restrict__ negAg,
        const float* __restrict__ x, float* __restrict__ out) {
    __shared__ float sK[9 * PB];         // 288 B
    __shared__ float sNegA[PB];

    int tid   = threadIdx.x;
    int pbase = (blockIdx.x & (PSPLIT - 1)) * PB;
    int g     = (blockIdx.x >> 4) * 256 + tid;   // strip id, grid exact

    if (tid < 9 * PB) sK[tid] = Kg[(tid / PB) * P_ + pbase + (tid % PB)];
    if (tid < PB)     sNegA[tid] = negAg[pbase + tid];
    __syncthreads();

    int n  = g / (HW_ / 4);
    int rr = g % (HW_ / 4);
    int r  = rr * 4;
    int h  = r / W_;
    int w  = r % W_;                     // w in {0,4,...,52}

    // activation window: rows h-1..h+1, cols w-1..w+4
    uint4 a[3][6];
    const uint4* ab = abits + (size_t)n * HW_;
    #pragma unroll
    for (int dr = 0; dr < 3; ++dr) {
        int hh = h + dr - 1;
        bool vr = (unsigned)hh < H_;
        #pragma unroll
        for (int dc = 0; dc < 6; ++dc) {
            int cc = w + dc - 1;
            a[dr][dc] = (vr && ((unsigned)cc < W_)) ? ab[hh * W_ + cc]
                                                    : make_uint4(0u, 0u, 0u, 0u);
        }
    }
    int chc  = (h == 0) ? 0 : ((h == H_ - 1) ? 2 : 1);
    int cls0 = chc * 3 + ((w == 0) ? 0 : 1);
    int cls1 = chc * 3 + 1;                          // middle pixels never at w-border
    int cls3 = chc * 3 + ((w + 3 == W_ - 1) ? 2 : 1);

    const float* xr = x   + ((size_t)n * P_ + pbase) * HW_ + r;
    float*       po = out + ((size_t)n * P_ + pbase) * HW_ + r;
    const uint4* wb = wbits4 + (size_t)pbase * 9;    // wave-uniform base

    for (int p = 0; p < PB; ++p) {
        float4 xv = *(const float4*)(xr + (size_t)p * HW_);
        int c0 = 0, c1 = 0, c2 = 0, c3 = 0;
        #pragma unroll
        for (int t = 0; t < 9; ++t) {
            uint4 wv = wb[p * 9 + t];                // uniform -> SGPRs
            int tr = t / 3, tc = t % 3;
            c0 += __popc(a[tr][tc+0].x ^ wv.x) + __popc(a[tr][tc+0].y ^ wv.y)
                + __popc(a[tr][tc+0].z ^ wv.z) + __popc(a[tr][tc+0].w ^ wv.w);
            c1 += __popc(a[tr][tc+1].x ^ wv.x) + __popc(a[tr][tc+1].y ^ wv.y)
                + __popc(a[tr][tc+1].z ^ wv.z) + __popc(a[tr][tc+1].w ^ wv.w);
            c2 += __popc(a[tr][tc+2].x ^ wv.x) + __popc(a[tr][tc+2].y ^ wv.y)
                + __popc(a[tr][tc+2].z ^ wv.z) + __popc(a[tr][tc+2].w ^ wv.w);
            c3 += __popc(a[tr][tc+3].x ^ wv.x) + __popc(a[tr][tc+3].y ^ wv.y)
                + __popc(a[tr][tc+3].z ^ wv.z) + __popc(a[tr][tc+3].w ^ wv.w);
        }
        float na = sNegA[p];
        float4 ov;
        ov.x = fmaf((float)c0, na, sK[cls0 * PB + p]) + xv.x;
        ov.y = fmaf((float)c1, na, sK[cls1 * PB + p]) + xv.y;
        ov.z = fmaf((float)c2, na, sK[cls1 * PB + p]) + xv.z;
        ov.w = fmaf((float)c3, na, sK[cls3 * PB + p]) + xv.w;
        *(float4*)(po + (size_t)p * HW_) = ov;
    }
}

extern "C" void kernel_launch(void* const* d_in, const int* in_sizes, int n_in,
                              void* d_out, int out_size, void* d_ws, size_t ws_size,
                              hipStream_t stream) {
    const float* x      = (const float*)d_in[0];
    const float* weight = (const float*)d_in[1];
    const float* bias   = (const float*)d_in[2];
    const float* gamma  = (const float*)d_in[3];
    const float* beta   = (const float*)d_in[4];
    const float* mean   = (const float*)d_in[5];
    const float* var    = (const float*)d_in[6];
    float* out = (float*)d_out;

    uint8_t*  ws    = (uint8_t*)d_ws;
    uint4*    abits = (uint4*)ws;
    uint32_t* wbits = (uint32_t*)(ws + ABITS_BYTES);
    float*    negA  = (float*)(ws + ABITS_BYTES + WBITS_BYTES);
    float*    K     = negA + P_;

    pack_x_kernel<<<(NPIX * 4) / 256, 256, 0, stream>>>(x, (uint32_t*)abits);
    pack_w_kernel<<<(P_ * 9 * 2 * 64) / 256, 256, 0, stream>>>(weight, wbits);
    ktab_kernel<<<5, 256, 0, stream>>>(wbits, bias, gamma, beta, mean, var, K, negA);
    bconv_kernel<<<(NGRP / 256) * PSPLIT, 256, 0, stream>>>(abits, (const uint4*)wbits, K, negA, x, out);
}

// Round 6
// 156.745 us; speedup vs baseline: 1.4699x; 1.0485x over previous
//
#include <hip/hip_runtime.h>
#include <stdint.h>

#define N_  32
#define C_  128
#define H_  56
#define W_  56
#define HW_ 3136
#define P_  128
#define NPIX (N_*HW_)           // 100352

using i32x4 = __attribute__((ext_vector_type(4))) int;

// ws layout (bytes):
//   abits : NPIX*16   = 1,605,632  (uint4 per pixel: 128 sign bits)
//   wI8   : P*1152    = 147,456    (i8 +1/-1 weights, [p][tap*128+c])
//   inv   : P*4
//   b0    : P*4
#define ABITS_BYTES (NPIX*16)
#define WI8_BYTES   (P_*1152)

// ------- pack x sign bits: word-plane-major, 2 pixels (float2) per thread ----
__global__ __launch_bounds__(256) void pack_x_kernel(const float* __restrict__ x,
                                                     uint32_t* __restrict__ abits_w) {
    int b      = blockIdx.x;
    int j      = b & 3;                              // 32-channel word
    int pairId = (b >> 2) * 256 + threadIdx.x;       // grid exact: 784 blocks
    int n      = pairId / (HW_ / 2);
    int r      = (pairId % (HW_ / 2)) * 2;
    const float* px = x + ((size_t)n * C_ + j * 32) * HW_ + r;
    uint32_t w0 = 0, w1 = 0;
    #pragma unroll
    for (int c = 0; c < 32; ++c) {
        float2 v = *(const float2*)(px + (size_t)c * HW_);
        if (v.x >= 0.f) w0 |= 1u << c;
        if (v.y >= 0.f) w1 |= 1u << c;
    }
    int pix = n * HW_ + r;
    abits_w[(size_t)pix * 4 + j]       = w0;
    abits_w[(size_t)(pix + 1) * 4 + j] = w1;
}

// ------- pack weights to i8 +1/-1 in [p][t*128+c] layout; fold BN ------------
__global__ __launch_bounds__(256) void wpack_kernel(const float* __restrict__ weight,
        const float* __restrict__ bias, const float* __restrict__ gamma,
        const float* __restrict__ beta, const float* __restrict__ mean,
        const float* __restrict__ var,
        uint32_t* __restrict__ wI8, float* __restrict__ invG, float* __restrict__ b0G) {
    int gid = blockIdx.x * 256 + threadIdx.x;        // 144 blocks = 36864 dwords
    int p   = gid / 288;
    int rem = gid % 288;
    int k   = rem * 4;                               // k = t*128 + c
    int tp  = k >> 7;
    int c   = k & 127;
    uint32_t d = 0;
    #pragma unroll
    for (int i2 = 0; i2 < 4; ++i2) {
        float v = weight[((size_t)p * C_ + c + i2) * 9 + tp];
        uint32_t by = (v >= 0.f) ? 0x01u : 0xFFu;
        d |= by << (8 * i2);
    }
    wI8[gid] = d;
    if (blockIdx.x == 0 && threadIdx.x < P_) {
        int pp = threadIdx.x;
        float inv = gamma[pp] * rsqrtf(var[pp] + 1e-5f);
        invG[pp] = inv;
        b0G[pp]  = bias[pp] * inv + beta[pp] - mean[pp] * inv;
    }
}

// ------- binary conv via i8 MFMA + BN + residual -----------------------------
// Block: 2 output rows x 64 cols (112 live pixels, N-tile=128) x 128 out-ch.
// Act bits -> +/-1 (0 for padding) i8 tile in LDS; weights staged per tap.
__global__ __launch_bounds__(256) void bconv_kernel(
        const uint4* __restrict__ abits, const uint4* __restrict__ wI8v,
        const float* __restrict__ invG, const float* __restrict__ b0G,
        const float* __restrict__ x, float* __restrict__ out) {
    __shared__ uint4 actT[4 * 68 * 8];   // 34816 B: [rho][colL][cblk^ (colL&7)]
    __shared__ uint4 sW[128 * 8];        // 16384 B: [p][cblk ^ (p&7)]
    __shared__ float sInv[P_], sB0[P_];

    int tid = threadIdx.x;
    int img = blockIdx.x / 28;
    int rp  = blockIdx.x % 28;
    int r0  = rp * 2;

    if (tid < P_) { sInv[tid] = invG[tid]; sB0[tid] = b0G[tid]; }

    // ---- expand act bits -> i8 tile (+1/-1, 0 outside image), swizzled ----
    for (int cell = tid; cell < 4 * 68; cell += 256) {
        int rho  = cell & 3;
        int colL = cell >> 2;                // w+1 coordinate
        int h    = r0 - 1 + rho;
        int wv   = colL - 1;
        bool valid = ((unsigned)h < H_) && ((unsigned)wv < W_);
        uint4 bits = valid ? abits[img * HW_ + h * W_ + wv] : make_uint4(0u, 0u, 0u, 0u);
        uint32_t bwv[4] = {bits.x, bits.y, bits.z, bits.w};
        int base16 = (rho * 68 + colL) * 8;
        int sz = colL & 7;
        #pragma unroll
        for (int cb = 0; cb < 8; ++cb) {
            uint32_t hw16 = (bwv[cb >> 1] >> ((cb & 1) * 16)) & 0xFFFFu;
            uint4 dq;
            uint32_t n0 = hw16 & 0xF, n1 = (hw16 >> 4) & 0xF,
                     n2 = (hw16 >> 8) & 0xF, n3 = (hw16 >> 12) & 0xF;
            // bit b -> byte: 1 -> 0x01, 0 -> 0xFF  (then zero if invalid)
            dq.x = 0xFFFFFFFFu ^ (((n0 * 0x204081u) & 0x01010101u) * 0xFEu);
            dq.y = 0xFFFFFFFFu ^ (((n1 * 0x204081u) & 0x01010101u) * 0xFEu);
            dq.z = 0xFFFFFFFFu ^ (((n2 * 0x204081u) & 0x01010101u) * 0xFEu);
            dq.w = 0xFFFFFFFFu ^ (((n3 * 0x204081u) & 0x01010101u) * 0xFEu);
            if (!valid) { dq.x = dq.y = dq.z = dq.w = 0u; }
            actT[base16 + (cb ^ sz)] = dq;
        }
    }

    int lane = tid & 63;
    int wi   = tid >> 6;
    int q    = lane >> 4;
    int l15  = lane & 15;
    int m0   = wi * 32;

    i32x4 acc[2][8];
    #pragma unroll
    for (int mi = 0; mi < 2; ++mi)
        #pragma unroll
        for (int j = 0; j < 8; ++j)
            #pragma unroll
            for (int e = 0; e < 4; ++e) acc[mi][j][e] = 0;

    int mA[2] = { m0 + l15, m0 + 16 + l15 };

    for (int t9 = 0; t9 < 9; ++t9) {
        __syncthreads();
        {   // stage this tap's weights: [128 p][128 c] i8, swizzled
            int p = tid >> 1, half = tid & 1;
            const uint4* src = wI8v + (size_t)p * 72 + t9 * 8 + half * 4;
            #pragma unroll
            for (int g2 = 0; g2 < 4; ++g2)
                sW[p * 8 + ((half * 4 + g2) ^ (p & 7))] = src[g2];
        }
        __syncthreads();
        int dh = t9 / 3, dw = t9 % 3;
        #pragma unroll
        for (int ks = 0; ks < 2; ++ks) {
            i32x4 af[2];
            #pragma unroll
            for (int mi = 0; mi < 2; ++mi) {
                int m = mA[mi];
                af[mi] = *(const i32x4*)&sW[m * 8 + ((ks * 4 + q) ^ (m & 7))];
            }
            #pragma unroll
            for (int j = 0; j < 8; ++j) {
                int n    = j * 16 + l15;
                int colL = (n & 63) + dw;
                int rho  = (n >> 6) + dh;
                i32x4 bf = *(const i32x4*)&actT[(rho * 68 + colL) * 8 + ((ks * 4 + q) ^ (colL & 7))];
                acc[0][j] = __builtin_amdgcn_mfma_i32_16x16x64_i8(af[0], bf, acc[0][j], 0, 0, 0);
                acc[1][j] = __builtin_amdgcn_mfma_i32_16x16x64_i8(af[1], bf, acc[1][j], 0, 0, 0);
            }
        }
    }

    // ---- epilogue: BN + residual, coalesced 64B segments ----
    float invR[2][4], b0R[2][4];
    #pragma unroll
    for (int mi = 0; mi < 2; ++mi)
        #pragma unroll
        for (int reg = 0; reg < 4; ++reg) {
            int m = m0 + mi * 16 + q * 4 + reg;
            invR[mi][reg] = sInv[m];
            b0R[mi][reg]  = sB0[m];
        }
    #pragma unroll
    for (int j = 0; j < 8; ++j) {
        int n = j * 16 + l15;
        int w = n & 63;
        if (w < W_) {
            int orow = r0 + (n >> 6);
            size_t pixOff = (size_t)img * P_ * HW_ + (size_t)orow * W_ + w;
            #pragma unroll
            for (int mi = 0; mi < 2; ++mi)
                #pragma unroll
                for (int reg = 0; reg < 4; ++reg) {
                    int m = m0 + mi * 16 + q * 4 + reg;
                    size_t off = pixOff + (size_t)m * HW_;
                    out[off] = (float)acc[mi][j][reg] * invR[mi][reg] + b0R[mi][reg] + x[off];
                }
        }
    }
}

extern "C" void kernel_launch(void* const* d_in, const int* in_sizes, int n_in,
                              void* d_out, int out_size, void* d_ws, size_t ws_size,
                              hipStream_t stream) {
    const float* x      = (const float*)d_in[0];
    const float* weight = (const float*)d_in[1];
    const float* bias   = (const float*)d_in[2];
    const float* gamma  = (const float*)d_in[3];
    const float* beta   = (const float*)d_in[4];
    const float* mean   = (const float*)d_in[5];
    const float* var    = (const float*)d_in[6];
    float* out = (float*)d_out;

    uint8_t*  ws    = (uint8_t*)d_ws;
    uint32_t* abits = (uint32_t*)ws;
    uint32_t* wI8   = (uint32_t*)(ws + ABITS_BYTES);
    float*    invG  = (float*)(ws + ABITS_BYTES + WI8_BYTES);
    float*    b0G   = invG + P_;

    pack_x_kernel<<<(NPIX / 2) * 4 / 256, 256, 0, stream>>>(x, abits);
    wpack_kernel<<<144, 256, 0, stream>>>(weight, bias, gamma, beta, mean, var, wI8, invG, b0G);
    bconv_kernel<<<32 * 28, 256, 0, stream>>>((const uint4*)abits, (const uint4*)wI8,
                                              invG, b0G, x, out);
}

// Round 7
// 148.590 us; speedup vs baseline: 1.5505x; 1.0549x over previous
//
#include <hip/hip_runtime.h>
#include <stdint.h>

#define N_  32
#define C_  128
#define H_  56
#define W_  56
#define HW_ 3136
#define P_  128
#define NPIX (N_*HW_)           // 100352

using i32x4 = __attribute__((ext_vector_type(4))) int;

// ws layout (bytes):
//   abits : NPIX*16   = 1,605,632  (uint4 per pixel: 128 sign bits)
//   wI8   : P*1152    = 147,456    (i8 +1/-1 weights, [p][tap*128+c])
//   inv   : P*4
//   b0    : P*4
#define ABITS_BYTES (NPIX*16)
#define WI8_BYTES   (P_*1152)

// ------- pack x sign bits: word-plane-major, 2 pixels (float2) per thread ----
__global__ __launch_bounds__(256) void pack_x_kernel(const float* __restrict__ x,
                                                     uint32_t* __restrict__ abits_w) {
    int b      = blockIdx.x;
    int j      = b & 3;                              // 32-channel word
    int pairId = (b >> 2) * 256 + threadIdx.x;       // grid exact: 784 blocks
    int n      = pairId / (HW_ / 2);
    int r      = (pairId % (HW_ / 2)) * 2;
    const float* px = x + ((size_t)n * C_ + j * 32) * HW_ + r;
    uint32_t w0 = 0, w1 = 0;
    #pragma unroll
    for (int c = 0; c < 32; ++c) {
        float2 v = *(const float2*)(px + (size_t)c * HW_);
        if (v.x >= 0.f) w0 |= 1u << c;
        if (v.y >= 0.f) w1 |= 1u << c;
    }
    int pix = n * HW_ + r;
    abits_w[(size_t)pix * 4 + j]       = w0;
    abits_w[(size_t)(pix + 1) * 4 + j] = w1;
}

// ------- pack weights to i8 +1/-1 in [p][t*128+c] layout; fold BN ------------
__global__ __launch_bounds__(256) void wpack_kernel(const float* __restrict__ weight,
        const float* __restrict__ bias, const float* __restrict__ gamma,
        const float* __restrict__ beta, const float* __restrict__ mean,
        const float* __restrict__ var,
        uint32_t* __restrict__ wI8, float* __restrict__ invG, float* __restrict__ b0G) {
    int gid = blockIdx.x * 256 + threadIdx.x;        // 144 blocks = 36864 dwords
    int p   = gid / 288;
    int rem = gid % 288;
    int k   = rem * 4;                               // k = t*128 + c
    int tp  = k >> 7;
    int c   = k & 127;
    uint32_t d = 0;
    #pragma unroll
    for (int i2 = 0; i2 < 4; ++i2) {
        float v = weight[((size_t)p * C_ + c + i2) * 9 + tp];
        uint32_t by = (v >= 0.f) ? 0x01u : 0xFFu;
        d |= by << (8 * i2);
    }
    wI8[gid] = d;
    if (blockIdx.x == 0 && threadIdx.x < P_) {
        int pp = threadIdx.x;
        float inv = gamma[pp] * rsqrtf(var[pp] + 1e-5f);
        invG[pp] = inv;
        b0G[pp]  = bias[pp] * inv + beta[pp] - mean[pp] * inv;
    }
}

// ------- binary conv via i8 MFMA + BN + residual -----------------------------
// Block: 2 output rows x 64 cols x 128 out-ch. Weights register-stationary
// (double-buffered global prefetch, wave-local); LDS holds only the act tile.
// ONE barrier per block -> latency-bound stalls of R6 removed.
__global__ __launch_bounds__(256) void bconv_kernel(
        const uint4* __restrict__ abits, const uint4* __restrict__ wI8v,
        const float* __restrict__ invG, const float* __restrict__ b0G,
        const float* __restrict__ x, float* __restrict__ out) {
    __shared__ uint4 actT[4 * 68 * 8];   // 34816 B: [rho][colL][cblk ^ (colL&7)]
    __shared__ float sInv[P_], sB0[P_];

    int tid = threadIdx.x;
    int img = blockIdx.x / 28;
    int rp  = blockIdx.x % 28;
    int r0  = rp * 2;

    if (tid < P_) { sInv[tid] = invG[tid]; sB0[tid] = b0G[tid]; }

    // ---- expand act bits -> i8 tile (+1/-1, 0 outside image), swizzled ----
    for (int cell = tid; cell < 4 * 68; cell += 256) {
        int rho  = cell & 3;
        int colL = cell >> 2;                // w+1 coordinate
        int h    = r0 - 1 + rho;
        int wv   = colL - 1;
        bool valid = ((unsigned)h < H_) && ((unsigned)wv < W_);
        uint4 bits = valid ? abits[img * HW_ + h * W_ + wv] : make_uint4(0u, 0u, 0u, 0u);
        uint32_t bwv[4] = {bits.x, bits.y, bits.z, bits.w};
        int base16 = (rho * 68 + colL) * 8;
        int sz = colL & 7;
        #pragma unroll
        for (int cb = 0; cb < 8; ++cb) {
            uint32_t hw16 = (bwv[cb >> 1] >> ((cb & 1) * 16)) & 0xFFFFu;
            uint4 dq;
            uint32_t n0 = hw16 & 0xF, n1 = (hw16 >> 4) & 0xF,
                     n2 = (hw16 >> 8) & 0xF, n3 = (hw16 >> 12) & 0xF;
            // bit b -> byte: 1 -> 0x01, 0 -> 0xFF  (then zero if invalid)
            dq.x = 0xFFFFFFFFu ^ (((n0 * 0x204081u) & 0x01010101u) * 0xFEu);
            dq.y = 0xFFFFFFFFu ^ (((n1 * 0x204081u) & 0x01010101u) * 0xFEu);
            dq.z = 0xFFFFFFFFu ^ (((n2 * 0x204081u) & 0x01010101u) * 0xFEu);
            dq.w = 0xFFFFFFFFu ^ (((n3 * 0x204081u) & 0x01010101u) * 0xFEu);
            if (!valid) { dq.x = dq.y = dq.z = dq.w = 0u; }
            actT[base16 + (cb ^ sz)] = dq;
        }
    }

    int lane = tid & 63;
    int wi   = tid >> 6;
    int q    = lane >> 4;
    int l15  = lane & 15;
    int m0   = wi * 32;

    // ---- A-fragments: register-stationary, double-buffered global prefetch --
    // uint4 index into wI8: p*72 + t*8 + ks*4 + q
    i32x4 aw[2][2][2];                   // [buf][mi][ks]
    #pragma unroll
    for (int mi = 0; mi < 2; ++mi)
        #pragma unroll
        for (int ks = 0; ks < 2; ++ks)
            aw[0][mi][ks] = *(const i32x4*)&wI8v[(size_t)(m0 + mi*16 + l15) * 72
                                                 + 0 * 8 + ks * 4 + q];

    i32x4 acc[2][8];
    #pragma unroll
    for (int mi = 0; mi < 2; ++mi)
        #pragma unroll
        for (int j = 0; j < 8; ++j)
            #pragma unroll
            for (int e = 0; e < 4; ++e) acc[mi][j][e] = 0;

    __syncthreads();                     // the ONLY barrier

    for (int t9 = 0; t9 < 9; ++t9) {
        int nb = t9 & 1;
        if (t9 < 8) {                    // prefetch next tap's weights
            #pragma unroll
            for (int mi = 0; mi < 2; ++mi)
                #pragma unroll
                for (int ks = 0; ks < 2; ++ks)
                    aw[nb ^ 1][mi][ks] = *(const i32x4*)&wI8v[(size_t)(m0 + mi*16 + l15) * 72
                                                              + (t9 + 1) * 8 + ks * 4 + q];
        }
        int dh = t9 / 3, dw = t9 % 3;
        #pragma unroll
        for (int ks = 0; ks < 2; ++ks) {
            #pragma unroll
            for (int j = 0; j < 8; ++j) {
                int n    = j * 16 + l15;
                int colL = (n & 63) + dw;
                int rho  = (n >> 6) + dh;
                i32x4 bf = *(const i32x4*)&actT[(rho * 68 + colL) * 8 + ((ks * 4 + q) ^ (colL & 7))];
                acc[0][j] = __builtin_amdgcn_mfma_i32_16x16x64_i8(aw[nb][0][ks], bf, acc[0][j], 0, 0, 0);
                acc[1][j] = __builtin_amdgcn_mfma_i32_16x16x64_i8(aw[nb][1][ks], bf, acc[1][j], 0, 0, 0);
            }
        }
    }

    // ---- epilogue: BN + residual, coalesced 64B segments ----
    float invR[2][4], b0R[2][4];
    #pragma unroll
    for (int mi = 0; mi < 2; ++mi)
        #pragma unroll
        for (int reg = 0; reg < 4; ++reg) {
            int m = m0 + mi * 16 + q * 4 + reg;
            invR[mi][reg] = sInv[m];
            b0R[mi][reg]  = sB0[m];
        }
    #pragma unroll
    for (int j = 0; j < 8; ++j) {
        int n = j * 16 + l15;
        int w = n & 63;
        if (w < W_) {
            int orow = r0 + (n >> 6);
            size_t pixOff = (size_t)img * P_ * HW_ + (size_t)orow * W_ + w;
            #pragma unroll
            for (int mi = 0; mi < 2; ++mi)
                #pragma unroll
                for (int reg = 0; reg < 4; ++reg) {
                    int m = m0 + mi * 16 + q * 4 + reg;
                    size_t off = pixOff + (size_t)m * HW_;
                    out[off] = (float)acc[mi][j][reg] * invR[mi][reg] + b0R[mi][reg] + x[off];
                }
        }
    }
}

extern "C" void kernel_launch(void* const* d_in, const int* in_sizes, int n_in,
                              void* d_out, int out_size, void* d_ws, size_t ws_size,
                              hipStream_t stream) {
    const float* x      = (const float*)d_in[0];
    const float* weight = (const float*)d_in[1];
    const float* bias   = (const float*)d_in[2];
    const float* gamma  = (const float*)d_in[3];
    const float* beta   = (const float*)d_in[4];
    const float* mean   = (const float*)d_in[5];
    const float* var    = (const float*)d_in[6];
    float* out = (float*)d_out;

    uint8_t*  ws    = (uint8_t*)d_ws;
    uint32_t* abits = (uint32_t*)ws;
    uint32_t* wI8   = (uint32_t*)(ws + ABITS_BYTES);
    float*    invG  = (float*)(ws + ABITS_BYTES + WI8_BYTES);
    float*    b0G   = invG + P_;

    pack_x_kernel<<<(NPIX / 2) * 4 / 256, 256, 0, stream>>>(x, abits);
    wpack_kernel<<<144, 256, 0, stream>>>(weight, bias, gamma, beta, mean, var, wI8, invG, b0G);
    bconv_kernel<<<32 * 28, 256, 0, stream>>>((const uint4*)abits, (const uint4*)wI8,
                                              invG, b0G, x, out);
}